// Round 2
// baseline (303.186 us; speedup 1.0000x reference)
//
#include <hip/hip_runtime.h>
#include <hip/hip_bf16.h>
#include <cstdint>

#define B_  8
#define T_  128
#define S_  400
#define D_  512
#define V_  50000
#define M_  (B_*T_)          // 1024
#define NT_ 391              // col tiles in GEMM (391*128 >= 50000)
#define EPS_LN 1e-6f

typedef __bf16 bf16x8 __attribute__((ext_vector_type(8)));
typedef float  f32x4  __attribute__((ext_vector_type(4)));
typedef unsigned short u16;
typedef unsigned short u16x8 __attribute__((ext_vector_type(8)));

__device__ __forceinline__ float bf2f(u16 u) {
    union { unsigned i; float f; } c; c.i = ((unsigned)u) << 16; return c.f;
}
__device__ __forceinline__ u16 f2bf(float f) {
    union { float f; unsigned i; } c; c.f = f;
    unsigned i = c.i;
    unsigned r = (i + 0x7FFFu + ((i >> 16) & 1u)) >> 16;   // round-nearest-even
    return (u16)r;
}

// block-wide reductions, blockDim.x == 256 (4 waves)
__device__ __forceinline__ float bsum(float v, float* sb) {
    #pragma unroll
    for (int o = 32; o; o >>= 1) v += __shfl_xor(v, o);
    __syncthreads();
    if ((threadIdx.x & 63) == 0) sb[threadIdx.x >> 6] = v;
    __syncthreads();
    return sb[0] + sb[1] + sb[2] + sb[3];
}
__device__ __forceinline__ float bmax(float v, float* sb) {
    #pragma unroll
    for (int o = 32; o; o >>= 1) v = fmaxf(v, __shfl_xor(v, o));
    __syncthreads();
    if ((threadIdx.x & 63) == 0) sb[threadIdx.x >> 6] = v;
    __syncthreads();
    return fmaxf(fmaxf(sb[0], sb[1]), fmaxf(sb[2], sb[3]));
}

// K1a: mw[b,s] = memory[b,s,:] . wh_w
__global__ void k_mw(const float* __restrict__ mem, const float* __restrict__ wh,
                     float* __restrict__ mw) {
    __shared__ float sb[4];
    int row = blockIdx.x;                     // b*S + s
    const float* mr = mem + (size_t)row * D_;
    int t = threadIdx.x;
    float2 m2 = *(const float2*)(mr + t * 2);
    float2 w2 = *(const float2*)(wh + t * 2);
    float v = m2.x * w2.x + m2.y * w2.y;
    float tot = bsum(v, sb);
    if (t == 0) mw[row] = tot;
}

// K1b: proj_w f32 -> bf16
__global__ void k_wconv(const float* __restrict__ w, u16* __restrict__ wb) {
    size_t i = ((size_t)blockIdx.x * 256 + threadIdx.x) * 8;
    float4 a = *(const float4*)(w + i);
    float4 b = *(const float4*)(w + i + 4);
    u16x8 o;
    o[0] = f2bf(a.x); o[1] = f2bf(a.y); o[2] = f2bf(a.z); o[3] = f2bf(a.w);
    o[4] = f2bf(b.x); o[5] = f2bf(b.y); o[6] = f2bf(b.z); o[7] = f2bf(b.w);
    *(u16x8*)(wb + i) = o;
}

// K2: per (b,t) row: LN stats -> A_bf16 row; logits -> p_gen
__global__ void k_rows(const float* __restrict__ x, const float* __restrict__ xt,
                       const float* __restrict__ attn, const float* __restrict__ mw,
                       const float* __restrict__ na, const float* __restrict__ nb,
                       const float* __restrict__ wsw, const float* __restrict__ wxw,
                       const float* __restrict__ whb, const float* __restrict__ wsb,
                       const float* __restrict__ wxb, const float* __restrict__ bp,
                       u16* __restrict__ Ab, float* __restrict__ pgen,
                       float* __restrict__ outp) {
    __shared__ float sb[4];
    int row = blockIdx.x;                 // b*T + t
    int b = row / T_;
    int tid = threadIdx.x;
    const float* xr  = x  + (size_t)row * D_;
    const float* xtr = xt + (size_t)row * D_;
    float2 xv = *(const float2*)(xr + tid * 2);
    float tsx  = bsum(xv.x + xv.y, sb);
    float tsx2 = bsum(xv.x * xv.x + xv.y * xv.y, sb);
    float mu  = tsx / (float)D_;
    float var = fmaxf(tsx2 / (float)D_ - mu * mu, 0.f);
    float rs  = 1.f / (sqrtf(var) + EPS_LN);
    float2 nav = *(const float2*)(na + tid * 2);
    float2 nbv = *(const float2*)(nb + tid * 2);
    u16 a0 = f2bf(nav.x * (xv.x - mu) * rs + nbv.x);
    u16 a1 = f2bf(nav.y * (xv.y - mu) * rs + nbv.y);
    ((unsigned*)(Ab + (size_t)row * D_))[tid] = (unsigned)a0 | ((unsigned)a1 << 16);
    // logits dots
    float2 wsv = *(const float2*)(wsw + tid * 2);
    float2 wxv = *(const float2*)(wxw + tid * 2);
    float2 xtv = *(const float2*)(xtr + tid * 2);
    float dot = xv.x * wsv.x + xv.y * wsv.y + xtv.x * wxv.x + xtv.y * wxv.y;
    if (tid < 200) {
        const float* ar  = attn + (size_t)row * S_;
        const float* mwb = mw + b * S_;
        float2 av = *(const float2*)(ar + tid * 2);
        float2 mv = *(const float2*)(mwb + tid * 2);
        dot += av.x * mv.x + av.y * mv.y;
    }
    float tdot = bsum(dot, sb);
    if (tid == 0) {
        float logit = tdot + whb[0] + wsb[0] + wxb[0] + bp[0];
        float p = 1.f / (1.f + __expf(-logit));
        pgen[row] = p;
        outp[row] = p;
    }
}

// K3: dec[m,v] = A[m,:] . W[v,:] + proj_b[v]  + fused per-(row, col-tile) softmax partials.
// LDS is fragment-major: each 16x32 MFMA subtile stored as 64 lanes x 16B contiguous
// (global source pre-permuted so global_load_lds linear dest matches; ds_read_b128
// then reads base+lane*16 -> conflict-free).
__global__ __launch_bounds__(256) void k_gemm(const u16* __restrict__ Ab,
                                              const u16* __restrict__ Wb,
                                              const float* __restrict__ projb,
                                              u16* __restrict__ dec,
                                              float* __restrict__ pmax,
                                              float* __restrict__ psum) {
    __shared__ __align__(16) u16 As[128 * 32];
    __shared__ __align__(16) u16 Bs[128 * 32];
    __shared__ float smax[2][128];
    __shared__ float ssum[2][128];
    int bid = blockIdx.x;
    int xcd = bid & 7, loc = bid >> 3;
    int wg = xcd * 391 + loc;             // bijective: 3128 = 8*391
    int mt = wg & 7, nt = wg >> 3;
    int brow = mt * 128, bcol = nt * 128;
    int tid = threadIdx.x, lane = tid & 63, wv = tid >> 6;
    int wm = wv >> 1, wn = wv & 1;
    int kq = lane >> 4, lr = lane & 15;
    f32x4 acc[4][4] = {};
    for (int kt = 0; kt < 16; ++kt) {
        #pragma unroll
        for (int i = 0; i < 2; ++i) {
            int flat = i * 4096 + tid * 16;            // bytes into 8KB tile
            int sub = flat >> 10;                      // 16-row subtile 0..7
            int l   = (flat >> 4) & 63;                // lane slot in subtile
            int kq2 = l >> 4, lr2 = l & 15;
            int arow = brow + sub * 16 + lr2;
            const u16* ga = Ab + (size_t)arow * 512 + kt * 32 + kq2 * 8;
            int vrow = bcol + sub * 16 + lr2; if (vrow >= V_) vrow = V_ - 1;
            const u16* gb = Wb + (size_t)vrow * 512 + kt * 32 + kq2 * 8;
            __builtin_amdgcn_global_load_lds(
                (const __attribute__((address_space(1))) unsigned*)ga,
                (__attribute__((address_space(3))) unsigned*)((char*)As + flat), 16, 0, 0);
            __builtin_amdgcn_global_load_lds(
                (const __attribute__((address_space(1))) unsigned*)gb,
                (__attribute__((address_space(3))) unsigned*)((char*)Bs + flat), 16, 0, 0);
        }
        __syncthreads();
        bf16x8 af[4], bfr[4];
        const bf16x8* Afp = (const bf16x8*)As;
        const bf16x8* Bfp = (const bf16x8*)Bs;
        #pragma unroll
        for (int m = 0; m < 4; ++m) af[m]  = Afp[(wm * 4 + m) * 64 + lane];
        #pragma unroll
        for (int n = 0; n < 4; ++n) bfr[n] = Bfp[(wn * 4 + n) * 64 + lane];
        #pragma unroll
        for (int m = 0; m < 4; ++m)
            #pragma unroll
            for (int n = 0; n < 4; ++n)
                acc[m][n] = __builtin_amdgcn_mfma_f32_16x16x32_bf16(af[m], bfr[n], acc[m][n], 0, 0, 0);
        __syncthreads();
    }
    // epilogue: bias + dec store + per-row (max, sumexp) over this block's 128 cols
    float pbn[4];
    int   cval[4];
    #pragma unroll
    for (int n = 0; n < 4; ++n) {
        int col = bcol + wn * 64 + n * 16 + lr;
        cval[n] = (col < V_);
        pbn[n]  = cval[n] ? projb[col] : 0.f;
    }
    #pragma unroll
    for (int m = 0; m < 4; ++m) {
        #pragma unroll
        for (int i = 0; i < 4; ++i) {
            int row128 = wm * 64 + m * 16 + kq * 4 + i;
            int grow = brow + row128;
            float dv[4];
            float mx = -1e30f;
            #pragma unroll
            for (int n = 0; n < 4; ++n) {
                dv[n] = cval[n] ? acc[m][n][i] + pbn[n] : -1e30f;
                mx = fmaxf(mx, dv[n]);
            }
            #pragma unroll
            for (int o = 1; o < 16; o <<= 1) mx = fmaxf(mx, __shfl_xor(mx, o));
            float se = 0.f;
            #pragma unroll
            for (int n = 0; n < 4; ++n) {
                if (cval[n]) {
                    se += __expf(dv[n] - mx);
                    dec[(size_t)grow * V_ + (bcol + wn * 64 + n * 16 + lr)] = f2bf(dv[n]);
                }
            }
            #pragma unroll
            for (int o = 1; o < 16; o <<= 1) se += __shfl_xor(se, o);
            if (lr == 0) { smax[wn][row128] = mx; ssum[wn][row128] = se; }
        }
    }
    __syncthreads();
    if (tid < 128) {
        float m0 = smax[0][tid], m1 = smax[1][tid];
        float M = fmaxf(m0, m1);
        float S = ssum[0][tid] * __expf(m0 - M) + ssum[1][tid] * __expf(m1 - M);
        size_t idx = (size_t)(brow + tid) * NT_ + nt;
        pmax[idx] = M;
        psum[idx] = S;
    }
}

// K4: combine partials: base[row] = gmax + log(sum_i psum_i * exp(pmax_i - gmax))
__global__ void k_reduce(const float* __restrict__ pmax, const float* __restrict__ psum,
                         float* __restrict__ base) {
    __shared__ float sb[4];
    int row = blockIdx.x;
    int t = threadIdx.x;
    const float* pm = pmax + (size_t)row * NT_;
    const float* ps = psum + (size_t)row * NT_;
    float mx = -1e30f;
    for (int j = t; j < NT_; j += 256) mx = fmaxf(mx, pm[j]);
    mx = bmax(mx, sb);
    float s = 0.f;
    for (int j = t; j < NT_; j += 256) s += ps[j] * __expf(pm[j] - mx);
    s = bsum(s, sb);
    if (t == 0) base[row] = mx + __logf(s);
}

// K5: out = log(p * exp(d - base) + 1e-12), 8 elems/thread
__global__ void k_final(const u16* __restrict__ dec, const float* __restrict__ pgen,
                        const float* __restrict__ base, float* __restrict__ out) {
    int row = blockIdx.y;
    int v0 = (blockIdx.x * 256 + threadIdx.x) * 8;
    if (v0 >= V_) return;
    float p  = pgen[row];
    float bs = base[row];
    u16x8 d = *(const u16x8*)(dec + (size_t)row * V_ + v0);
    float4 o0, o1;
    o0.x = __logf(p * __expf(bf2f(d[0]) - bs) + 1e-12f);
    o0.y = __logf(p * __expf(bf2f(d[1]) - bs) + 1e-12f);
    o0.z = __logf(p * __expf(bf2f(d[2]) - bs) + 1e-12f);
    o0.w = __logf(p * __expf(bf2f(d[3]) - bs) + 1e-12f);
    o1.x = __logf(p * __expf(bf2f(d[4]) - bs) + 1e-12f);
    o1.y = __logf(p * __expf(bf2f(d[5]) - bs) + 1e-12f);
    o1.z = __logf(p * __expf(bf2f(d[6]) - bs) + 1e-12f);
    o1.w = __logf(p * __expf(bf2f(d[7]) - bs) + 1e-12f);
    float* op = out + (size_t)row * V_ + v0;
    *(float4*)op = o0;
    *(float4*)(op + 4) = o1;
}

// K6: overwrite src columns with the pointer-mix term
__global__ void k_fix(const int* __restrict__ src, const float* __restrict__ attn,
                      const u16* __restrict__ dec, const float* __restrict__ pgen,
                      const float* __restrict__ base, float* __restrict__ out) {
    int b = blockIdx.x / S_, s = blockIdx.x % S_;
    const int* sr = src + b * S_;
    int v = sr[s];
    for (int s2 = 0; s2 < s; ++s2)
        if (sr[s2] == v) return;          // not first occurrence (uniform branch)
    int t = threadIdx.x;                  // 0..127
    float enc = 0.f;
    const float* ar = attn + (size_t)(b * T_ + t) * S_;
    for (int s2 = s; s2 < S_; ++s2)
        if (sr[s2] == v) enc += ar[s2];
    int row = b * T_ + t;
    float p  = pgen[row];
    float bs = base[row];
    float d  = bf2f(dec[(size_t)row * V_ + v]);
    out[(size_t)row * V_ + v] = __logf(p * __expf(d - bs) + (1.f - p) * enc + 1e-12f);
}

extern "C" void kernel_launch(void* const* d_in, const int* in_sizes, int n_in,
                              void* d_out, int out_size, void* d_ws, size_t ws_size,
                              hipStream_t stream) {
    const float* x    = (const float*)d_in[0];
    const float* xt   = (const float*)d_in[1];
    const float* mem  = (const float*)d_in[2];
    const float* attn = (const float*)d_in[3];
    const int*   src  = (const int*)d_in[4];
    const float* na   = (const float*)d_in[5];
    const float* nb   = (const float*)d_in[6];
    const float* pw   = (const float*)d_in[7];
    const float* pb   = (const float*)d_in[8];
    const float* whw  = (const float*)d_in[9];
    const float* whb  = (const float*)d_in[10];
    const float* wsw  = (const float*)d_in[11];
    const float* wsb  = (const float*)d_in[12];
    const float* wxw  = (const float*)d_in[13];
    const float* wxb  = (const float*)d_in[14];
    const float* bp   = (const float*)d_in[15];

    char* ws = (char*)d_ws;
    u16*   Wb   = (u16*)(ws + 0);                 // 51,200,000 B
    u16*   Ab   = (u16*)(ws + 51200000);          //  1,048,576 B
    u16*   dec  = (u16*)(ws + 52248576);          // 102,400,000 B
    float* pmax = (float*)(ws + 154648576);       //  1,601,536 B
    float* psum = (float*)(ws + 156250112);       //  1,601,536 B
    float* mw   = (float*)(ws + 157851648);       //     12,800 B
    float* pgen = (float*)(ws + 157864448);       //      4,096 B
    float* base = (float*)(ws + 157868544);       //      4,096 B
    float* out  = (float*)d_out;
    float* outp = out + (size_t)M_ * V_;          // p_gen section

    k_mw    <<<B_ * S_, 256, 0, stream>>>(mem, whw, mw);
    k_wconv <<<12500, 256, 0, stream>>>(pw, Wb);
    k_rows  <<<M_, 256, 0, stream>>>(x, xt, attn, mw, na, nb, wsw, wxw,
                                     whb, wsb, wxb, bp, Ab, pgen, outp);
    k_gemm  <<<3128, 256, 0, stream>>>(Ab, Wb, pb, dec, pmax, psum);
    k_reduce<<<M_, 256, 0, stream>>>(pmax, psum, base);
    k_final <<<dim3(25, M_), 256, 0, stream>>>(dec, pgen, base, out);
    k_fix   <<<B_ * S_, 128, 0, stream>>>(src, attn, dec, pgen, base, out);
}

// Round 3
// 284.944 us; speedup vs baseline: 1.0640x; 1.0640x over previous
//
#include <hip/hip_runtime.h>
#include <hip/hip_bf16.h>
#include <cstdint>

#define B_  8
#define T_  128
#define S_  400
#define D_  512
#define V_  50000
#define M_  (B_*T_)          // 1024
#define NT_ 391              // col tiles in GEMM (391*128 >= 50000)
#define EPS_LN 1e-6f

typedef __bf16 bf16x8 __attribute__((ext_vector_type(8)));
typedef float  f32x4  __attribute__((ext_vector_type(4)));
typedef unsigned short u16;
typedef unsigned short u16x8 __attribute__((ext_vector_type(8)));

__device__ __forceinline__ float bf2f(u16 u) {
    union { unsigned i; float f; } c; c.i = ((unsigned)u) << 16; return c.f;
}
__device__ __forceinline__ u16 f2bf(float f) {
    union { float f; unsigned i; } c; c.f = f;
    unsigned i = c.i;
    unsigned r = (i + 0x7FFFu + ((i >> 16) & 1u)) >> 16;   // round-nearest-even
    return (u16)r;
}

// block-wide reductions, blockDim.x == 256 (4 waves)
__device__ __forceinline__ float bsum(float v, float* sb) {
    #pragma unroll
    for (int o = 32; o; o >>= 1) v += __shfl_xor(v, o);
    __syncthreads();
    if ((threadIdx.x & 63) == 0) sb[threadIdx.x >> 6] = v;
    __syncthreads();
    return sb[0] + sb[1] + sb[2] + sb[3];
}

// K1a: mw[b,s] = memory[b,s,:] . wh_w
__global__ void k_mw(const float* __restrict__ mem, const float* __restrict__ wh,
                     float* __restrict__ mw) {
    __shared__ float sb[4];
    int row = blockIdx.x;                     // b*S + s
    const float* mr = mem + (size_t)row * D_;
    int t = threadIdx.x;
    float2 m2 = *(const float2*)(mr + t * 2);
    float2 w2 = *(const float2*)(wh + t * 2);
    float v = m2.x * w2.x + m2.y * w2.y;
    float tot = bsum(v, sb);
    if (t == 0) mw[row] = tot;
}

// K1b: proj_w f32 -> bf16
__global__ void k_wconv(const float* __restrict__ w, u16* __restrict__ wb) {
    size_t i = ((size_t)blockIdx.x * 256 + threadIdx.x) * 8;
    float4 a = *(const float4*)(w + i);
    float4 b = *(const float4*)(w + i + 4);
    u16x8 o;
    o[0] = f2bf(a.x); o[1] = f2bf(a.y); o[2] = f2bf(a.z); o[3] = f2bf(a.w);
    o[4] = f2bf(b.x); o[5] = f2bf(b.y); o[6] = f2bf(b.z); o[7] = f2bf(b.w);
    *(u16x8*)(wb + i) = o;
}

// K2: per (b,t) row: LN stats -> A_bf16 row; logits -> p_gen
__global__ void k_rows(const float* __restrict__ x, const float* __restrict__ xt,
                       const float* __restrict__ attn, const float* __restrict__ mw,
                       const float* __restrict__ na, const float* __restrict__ nb,
                       const float* __restrict__ wsw, const float* __restrict__ wxw,
                       const float* __restrict__ whb, const float* __restrict__ wsb,
                       const float* __restrict__ wxb, const float* __restrict__ bp,
                       u16* __restrict__ Ab, float* __restrict__ pgen,
                       float* __restrict__ outp) {
    __shared__ float sb[4];
    int row = blockIdx.x;                 // b*T + t
    int b = row / T_;
    int tid = threadIdx.x;
    const float* xr  = x  + (size_t)row * D_;
    const float* xtr = xt + (size_t)row * D_;
    float2 xv = *(const float2*)(xr + tid * 2);
    float tsx  = bsum(xv.x + xv.y, sb);
    float tsx2 = bsum(xv.x * xv.x + xv.y * xv.y, sb);
    float mu  = tsx / (float)D_;
    float var = fmaxf(tsx2 / (float)D_ - mu * mu, 0.f);
    float rs  = 1.f / (sqrtf(var) + EPS_LN);
    float2 nav = *(const float2*)(na + tid * 2);
    float2 nbv = *(const float2*)(nb + tid * 2);
    u16 a0 = f2bf(nav.x * (xv.x - mu) * rs + nbv.x);
    u16 a1 = f2bf(nav.y * (xv.y - mu) * rs + nbv.y);
    ((unsigned*)(Ab + (size_t)row * D_))[tid] = (unsigned)a0 | ((unsigned)a1 << 16);
    // logits dots
    float2 wsv = *(const float2*)(wsw + tid * 2);
    float2 wxv = *(const float2*)(wxw + tid * 2);
    float2 xtv = *(const float2*)(xtr + tid * 2);
    float dot = xv.x * wsv.x + xv.y * wsv.y + xtv.x * wxv.x + xtv.y * wxv.y;
    if (tid < 200) {
        const float* ar  = attn + (size_t)row * S_;
        const float* mwb = mw + b * S_;
        float2 av = *(const float2*)(ar + tid * 2);
        float2 mv = *(const float2*)(mwb + tid * 2);
        dot += av.x * mv.x + av.y * mv.y;
    }
    float tdot = bsum(dot, sb);
    if (tid == 0) {
        float logit = tdot + whb[0] + wsb[0] + wxb[0] + bp[0];
        float p = 1.f / (1.f + __expf(-logit));
        pgen[row] = p;
        outp[row] = p;
    }
}

// K3: dec[m,v] = A[m,:] . W[v,:] + proj_b[v], double-buffered prefetch K-loop,
// fragment-major LDS (conflict-free ds_read_b128), LDS-staged coalesced output,
// fused per-(row, col-tile) sum-exp partials (no max subtraction: |dec| < ~7).
__global__ __launch_bounds__(256) void k_gemm(const u16* __restrict__ Ab,
                                              const u16* __restrict__ Wb,
                                              const float* __restrict__ projb,
                                              u16* __restrict__ dec,
                                              float* __restrict__ psum) {
    // smem layout: [0,16384) = buf0 (A:0-8K, B:8-16K); [16384,32768) = buf1
    // epilogue reuse: Os[128][136] u16 = 34816 B; ssum at 34816 (1KB)
    __shared__ __align__(16) char smem[35840];
    int bid = blockIdx.x;
    int xcd = bid & 7, loc = bid >> 3;
    int wg = xcd * NT_ + loc;             // bijective: 3128 = 8*391
    int mt = wg & 7, nt = wg >> 3;
    int brow = mt * 128, bcol = nt * 128;
    int tid = threadIdx.x, lane = tid & 63, wv = tid >> 6;
    int wm = wv >> 1, wn = wv & 1;
    int kq = lane >> 4, lr = lane & 15;

    // per-thread staging source offsets (fragment-major pre-permutation, m173)
    size_t aoff[2], boff[2];
    int flatoff[2];
    #pragma unroll
    for (int i = 0; i < 2; ++i) {
        int flat = i * 4096 + tid * 16;            // bytes into 8KB half
        flatoff[i] = flat;
        int sub = flat >> 10;                      // 16-row subtile 0..7
        int l   = (flat >> 4) & 63;                // lane slot in subtile
        int kq2 = l >> 4, lr2 = l & 15;
        int arow = brow + sub * 16 + lr2;
        int vrow = bcol + sub * 16 + lr2; if (vrow >= V_) vrow = V_ - 1;
        aoff[i] = (size_t)arow * 512 + kq2 * 8;
        boff[i] = (size_t)vrow * 512 + kq2 * 8;
    }

#define STAGE(buf, kt) { \
    char* ab = smem + (buf) * 16384; \
    _Pragma("unroll") \
    for (int i = 0; i < 2; ++i) { \
        __builtin_amdgcn_global_load_lds( \
            (const __attribute__((address_space(1))) unsigned*)(Ab + aoff[i] + (size_t)(kt) * 32), \
            (__attribute__((address_space(3))) unsigned*)(ab + flatoff[i]), 16, 0, 0); \
        __builtin_amdgcn_global_load_lds( \
            (const __attribute__((address_space(1))) unsigned*)(Wb + boff[i] + (size_t)(kt) * 32), \
            (__attribute__((address_space(3))) unsigned*)(ab + 8192 + flatoff[i]), 16, 0, 0); \
    } }

    f32x4 acc[4][4] = {};
    STAGE(0, 0);
    __syncthreads();
    for (int kt = 0; kt < 16; ++kt) {
        int cur = kt & 1;
        if (kt < 15) STAGE(cur ^ 1, kt + 1);       // prefetch flies under compute
        const bf16x8* Afp = (const bf16x8*)(smem + cur * 16384);
        const bf16x8* Bfp = (const bf16x8*)(smem + cur * 16384 + 8192);
        bf16x8 af[4], bfr[4];
        #pragma unroll
        for (int m = 0; m < 4; ++m) af[m]  = Afp[(wm * 4 + m) * 64 + lane];
        #pragma unroll
        for (int n = 0; n < 4; ++n) bfr[n] = Bfp[(wn * 4 + n) * 64 + lane];
        #pragma unroll
        for (int m = 0; m < 4; ++m)
            #pragma unroll
            for (int n = 0; n < 4; ++n)
                acc[m][n] = __builtin_amdgcn_mfma_f32_16x16x32_bf16(af[m], bfr[n], acc[m][n], 0, 0, 0);
        __syncthreads();   // drains vmcnt(0): prefetched tile ready; LDS safe to reuse
    }
#undef STAGE

    // epilogue: bias, sum-exp partials (no max), Os staging for coalesced stores
    float pbn[4]; int cvaln[4];
    #pragma unroll
    for (int n = 0; n < 4; ++n) {
        int col = bcol + wn * 64 + n * 16 + lr;
        cvaln[n] = (col < V_);
        pbn[n] = cvaln[n] ? projb[col] : 0.f;
    }
    u16 (*Os)[136] = (u16(*)[136])smem;
    float* ssum = (float*)(smem + 34816);          // [2][128]
    #pragma unroll
    for (int m = 0; m < 4; ++m) {
        #pragma unroll
        for (int i = 0; i < 4; ++i) {
            int row128 = wm * 64 + m * 16 + kq * 4 + i;
            float se = 0.f;
            #pragma unroll
            for (int n = 0; n < 4; ++n) {
                float dv = acc[m][n][i] + pbn[n];
                if (cvaln[n]) se += __expf(dv);
                Os[row128][wn * 64 + n * 16 + lr] = f2bf(dv);
            }
            #pragma unroll
            for (int o = 1; o < 16; o <<= 1) se += __shfl_xor(se, o);
            if (lr == 0) ssum[wn * 128 + row128] = se;
        }
    }
    __syncthreads();
    if (tid < 128) {
        psum[(size_t)(brow + tid) * NT_ + nt] = ssum[tid] + ssum[128 + tid];
    }
    #pragma unroll
    for (int j = 0; j < 8; ++j) {
        int row = j * 16 + (tid >> 4);
        int c8 = (tid & 15) * 8;
        int gcol = bcol + c8;
        if (gcol + 8 <= V_) {                      // V_ % 8 == 0: chunk all-or-nothing
            u16x8 v = *(const u16x8*)&Os[row][c8];
            *(u16x8*)(dec + (size_t)(brow + row) * V_ + gcol) = v;
        }
    }
}

// K4: base[row] = log(sum_i psum_i)
__global__ void k_reduce(const float* __restrict__ psum, float* __restrict__ base) {
    __shared__ float sb[4];
    int row = blockIdx.x;
    int t = threadIdx.x;
    const float* ps = psum + (size_t)row * NT_;
    float s = 0.f;
    for (int j = t; j < NT_; j += 256) s += ps[j];
    s = bsum(s, sb);
    if (t == 0) base[row] = __logf(s);
}

// K5: out = log(p * exp(d - base) + 1e-12), 8 elems/thread
__global__ void k_final(const u16* __restrict__ dec, const float* __restrict__ pgen,
                        const float* __restrict__ base, float* __restrict__ out) {
    int row = blockIdx.y;
    int v0 = (blockIdx.x * 256 + threadIdx.x) * 8;
    if (v0 >= V_) return;
    float p  = pgen[row];
    float bs = base[row];
    u16x8 d = *(const u16x8*)(dec + (size_t)row * V_ + v0);
    float4 o0, o1;
    o0.x = __logf(p * __expf(bf2f(d[0]) - bs) + 1e-12f);
    o0.y = __logf(p * __expf(bf2f(d[1]) - bs) + 1e-12f);
    o0.z = __logf(p * __expf(bf2f(d[2]) - bs) + 1e-12f);
    o0.w = __logf(p * __expf(bf2f(d[3]) - bs) + 1e-12f);
    o1.x = __logf(p * __expf(bf2f(d[4]) - bs) + 1e-12f);
    o1.y = __logf(p * __expf(bf2f(d[5]) - bs) + 1e-12f);
    o1.z = __logf(p * __expf(bf2f(d[6]) - bs) + 1e-12f);
    o1.w = __logf(p * __expf(bf2f(d[7]) - bs) + 1e-12f);
    float* op = out + (size_t)row * V_ + v0;
    *(float4*)op = o0;
    *(float4*)(op + 4) = o1;
}

// K6: overwrite src columns with the pointer-mix term
__global__ void k_fix(const int* __restrict__ src, const float* __restrict__ attn,
                      const u16* __restrict__ dec, const float* __restrict__ pgen,
                      const float* __restrict__ base, float* __restrict__ out) {
    int b = blockIdx.x / S_, s = blockIdx.x % S_;
    const int* sr = src + b * S_;
    int v = sr[s];
    for (int s2 = 0; s2 < s; ++s2)
        if (sr[s2] == v) return;          // not first occurrence (uniform branch)
    int t = threadIdx.x;                  // 0..127
    float enc = 0.f;
    const float* ar = attn + (size_t)(b * T_ + t) * S_;
    for (int s2 = s; s2 < S_; ++s2)
        if (sr[s2] == v) enc += ar[s2];
    int row = b * T_ + t;
    float p  = pgen[row];
    float bs = base[row];
    float d  = bf2f(dec[(size_t)row * V_ + v]);
    out[(size_t)row * V_ + v] = __logf(p * __expf(d - bs) + (1.f - p) * enc + 1e-12f);
}

extern "C" void kernel_launch(void* const* d_in, const int* in_sizes, int n_in,
                              void* d_out, int out_size, void* d_ws, size_t ws_size,
                              hipStream_t stream) {
    const float* x    = (const float*)d_in[0];
    const float* xt   = (const float*)d_in[1];
    const float* mem  = (const float*)d_in[2];
    const float* attn = (const float*)d_in[3];
    const int*   src  = (const int*)d_in[4];
    const float* na   = (const float*)d_in[5];
    const float* nb   = (const float*)d_in[6];
    const float* pw   = (const float*)d_in[7];
    const float* pb   = (const float*)d_in[8];
    const float* whw  = (const float*)d_in[9];
    const float* whb  = (const float*)d_in[10];
    const float* wsw  = (const float*)d_in[11];
    const float* wsb  = (const float*)d_in[12];
    const float* wxw  = (const float*)d_in[13];
    const float* wxb  = (const float*)d_in[14];
    const float* bp   = (const float*)d_in[15];

    char* ws = (char*)d_ws;
    u16*   Wb   = (u16*)(ws + 0);                 // 51,200,000 B
    u16*   Ab   = (u16*)(ws + 51200000);          //  1,048,576 B
    u16*   dec  = (u16*)(ws + 52248576);          // 102,400,000 B
    float* psum = (float*)(ws + 154648576);       //  1,601,536 B
    float* mw   = (float*)(ws + 156250112);       //     12,800 B
    float* pgen = (float*)(ws + 156262912);       //      4,096 B
    float* base = (float*)(ws + 156267008);       //      4,096 B
    float* out  = (float*)d_out;
    float* outp = out + (size_t)M_ * V_;          // p_gen section

    k_mw    <<<B_ * S_, 256, 0, stream>>>(mem, whw, mw);
    k_wconv <<<12500, 256, 0, stream>>>(pw, Wb);
    k_rows  <<<M_, 256, 0, stream>>>(x, xt, attn, mw, na, nb, wsw, wxw,
                                     whb, wsb, wxb, bp, Ab, pgen, outp);
    k_gemm  <<<3128, 256, 0, stream>>>(Ab, Wb, pb, dec, psum);
    k_reduce<<<M_, 256, 0, stream>>>(psum, base);
    k_final <<<dim3(25, M_), 256, 0, stream>>>(dec, pgen, base, out);
    k_fix   <<<B_ * S_, 128, 0, stream>>>(src, attn, dec, pgen, base, out);
}

// Round 4
// 268.251 us; speedup vs baseline: 1.1302x; 1.0622x over previous
//
#include <hip/hip_runtime.h>
#include <hip/hip_bf16.h>
#include <cstdint>

#define B_  8
#define T_  128
#define S_  400
#define D_  512
#define V_  50000
#define M_  (B_*T_)          // 1024
#define NT_ 391              // col tiles in GEMM (391*128 >= 50000)
#define EPS_LN 1e-6f

typedef __bf16 bf16x8 __attribute__((ext_vector_type(8)));
typedef float  f32x4  __attribute__((ext_vector_type(4)));
typedef unsigned short u16;
typedef unsigned short u16x8 __attribute__((ext_vector_type(8)));

__device__ __forceinline__ float bf2f(u16 u) {
    union { unsigned i; float f; } c; c.i = ((unsigned)u) << 16; return c.f;
}
__device__ __forceinline__ u16 f2bf(float f) {
    union { float f; unsigned i; } c; c.f = f;
    unsigned i = c.i;
    unsigned r = (i + 0x7FFFu + ((i >> 16) & 1u)) >> 16;   // round-nearest-even
    return (u16)r;
}

// block-wide reductions, blockDim.x == 256 (4 waves)
__device__ __forceinline__ float bsum(float v, float* sb) {
    #pragma unroll
    for (int o = 32; o; o >>= 1) v += __shfl_xor(v, o);
    __syncthreads();
    if ((threadIdx.x & 63) == 0) sb[threadIdx.x >> 6] = v;
    __syncthreads();
    return sb[0] + sb[1] + sb[2] + sb[3];
}

// K1a: mw[b,s] = memory[b,s,:] . wh_w
__global__ void k_mw(const float* __restrict__ mem, const float* __restrict__ wh,
                     float* __restrict__ mw) {
    __shared__ float sb[4];
    int row = blockIdx.x;                     // b*S + s
    const float* mr = mem + (size_t)row * D_;
    int t = threadIdx.x;
    float2 m2 = *(const float2*)(mr + t * 2);
    float2 w2 = *(const float2*)(wh + t * 2);
    float v = m2.x * w2.x + m2.y * w2.y;
    float tot = bsum(v, sb);
    if (t == 0) mw[row] = tot;
}

// K1b: proj_w f32 -> bf16
__global__ void k_wconv(const float* __restrict__ w, u16* __restrict__ wb) {
    size_t i = ((size_t)blockIdx.x * 256 + threadIdx.x) * 8;
    float4 a = *(const float4*)(w + i);
    float4 b = *(const float4*)(w + i + 4);
    u16x8 o;
    o[0] = f2bf(a.x); o[1] = f2bf(a.y); o[2] = f2bf(a.z); o[3] = f2bf(a.w);
    o[4] = f2bf(b.x); o[5] = f2bf(b.y); o[6] = f2bf(b.z); o[7] = f2bf(b.w);
    *(u16x8*)(wb + i) = o;
}

// K2: per (b,t) row: LN stats -> A_bf16 row; logits -> p_gen
__global__ void k_rows(const float* __restrict__ x, const float* __restrict__ xt,
                       const float* __restrict__ attn, const float* __restrict__ mw,
                       const float* __restrict__ na, const float* __restrict__ nb,
                       const float* __restrict__ wsw, const float* __restrict__ wxw,
                       const float* __restrict__ whb, const float* __restrict__ wsb,
                       const float* __restrict__ wxb, const float* __restrict__ bp,
                       u16* __restrict__ Ab, float* __restrict__ pgen,
                       float* __restrict__ outp) {
    __shared__ float sb[4];
    int row = blockIdx.x;                 // b*T + t
    int b = row / T_;
    int tid = threadIdx.x;
    const float* xr  = x  + (size_t)row * D_;
    const float* xtr = xt + (size_t)row * D_;
    float2 xv = *(const float2*)(xr + tid * 2);
    float tsx  = bsum(xv.x + xv.y, sb);
    float tsx2 = bsum(xv.x * xv.x + xv.y * xv.y, sb);
    float mu  = tsx / (float)D_;
    float var = fmaxf(tsx2 / (float)D_ - mu * mu, 0.f);
    float rs  = 1.f / (sqrtf(var) + EPS_LN);
    float2 nav = *(const float2*)(na + tid * 2);
    float2 nbv = *(const float2*)(nb + tid * 2);
    u16 a0 = f2bf(nav.x * (xv.x - mu) * rs + nbv.x);
    u16 a1 = f2bf(nav.y * (xv.y - mu) * rs + nbv.y);
    ((unsigned*)(Ab + (size_t)row * D_))[tid] = (unsigned)a0 | ((unsigned)a1 << 16);
    // logits dots
    float2 wsv = *(const float2*)(wsw + tid * 2);
    float2 wxv = *(const float2*)(wxw + tid * 2);
    float2 xtv = *(const float2*)(xtr + tid * 2);
    float dot = xv.x * wsv.x + xv.y * wsv.y + xtv.x * wxv.x + xtv.y * wxv.y;
    if (tid < 200) {
        const float* ar  = attn + (size_t)row * S_;
        const float* mwb = mw + b * S_;
        float2 av = *(const float2*)(ar + tid * 2);
        float2 mv = *(const float2*)(mwb + tid * 2);
        dot += av.x * mv.x + av.y * mv.y;
    }
    float tdot = bsum(dot, sb);
    if (tid == 0) {
        float logit = tdot + whb[0] + wsb[0] + wxb[0] + bp[0];
        float p = 1.f / (1.f + __expf(-logit));
        pgen[row] = p;
        outp[row] = p;
    }
}

// K3: dec[m,v] = A[m,:] . W[v,:] + proj_b[v].
// Depth-2 pipelined K-loop with COUNTED vmcnt (never 0 until the last step):
//   top:  wait vmcnt(4) [tile kt landed everywhere after barrier], s_barrier
//   body: ds_read frags + 16 MFMA
//   end:  s_barrier (all waves done reading buf), then STAGE(kt+2) into it
// Fragment-major LDS (conflict-free ds_read_b128), LDS-staged coalesced output,
// fused per-(row, col-tile) sum-exp partials (no max subtraction: |dec| < ~7).
__global__ __launch_bounds__(256) void k_gemm(const u16* __restrict__ Ab,
                                              const u16* __restrict__ Wb,
                                              const float* __restrict__ projb,
                                              u16* __restrict__ dec,
                                              float* __restrict__ psum) {
    __shared__ __align__(16) char smem[35840];
    int bid = blockIdx.x;
    int xcd = bid & 7, loc = bid >> 3;
    int wg = xcd * NT_ + loc;             // bijective: 3128 = 8*391
    int mt = wg & 7, nt = wg >> 3;
    int brow = mt * 128, bcol = nt * 128;
    int tid = threadIdx.x, lane = tid & 63, wv = tid >> 6;
    int wm = wv >> 1, wn = wv & 1;
    int kq = lane >> 4, lr = lane & 15;

    // per-thread staging source offsets (fragment-major pre-permutation, m173)
    size_t aoff[2], boff[2];
    int flatoff[2];
    #pragma unroll
    for (int i = 0; i < 2; ++i) {
        int flat = i * 4096 + tid * 16;            // bytes into 8KB half
        flatoff[i] = flat;
        int sub = flat >> 10;                      // 16-row subtile 0..7
        int l   = (flat >> 4) & 63;                // lane slot in subtile
        int kq2 = l >> 4, lr2 = l & 15;
        int arow = brow + sub * 16 + lr2;
        int vrow = bcol + sub * 16 + lr2; if (vrow >= V_) vrow = V_ - 1;
        aoff[i] = (size_t)arow * 512 + kq2 * 8;
        boff[i] = (size_t)vrow * 512 + kq2 * 8;
    }

#define STAGE(buf, kt) { \
    char* ab = smem + (buf) * 16384; \
    _Pragma("unroll") \
    for (int i = 0; i < 2; ++i) { \
        __builtin_amdgcn_global_load_lds( \
            (const __attribute__((address_space(1))) unsigned*)(Ab + aoff[i] + (size_t)(kt) * 32), \
            (__attribute__((address_space(3))) unsigned*)(ab + flatoff[i]), 16, 0, 0); \
        __builtin_amdgcn_global_load_lds( \
            (const __attribute__((address_space(1))) unsigned*)(Wb + boff[i] + (size_t)(kt) * 32), \
            (__attribute__((address_space(3))) unsigned*)(ab + 8192 + flatoff[i]), 16, 0, 0); \
    } }

    f32x4 acc[4][4] = {};
    STAGE(0, 0);
    STAGE(1, 1);
    for (int kt = 0; kt < 16; ++kt) {
        int cur = kt & 1;
        if (kt < 15) { asm volatile("s_waitcnt vmcnt(4)" ::: "memory"); }
        else         { asm volatile("s_waitcnt vmcnt(0)" ::: "memory"); }
        __builtin_amdgcn_s_barrier();
        __builtin_amdgcn_sched_barrier(0);
        const bf16x8* Afp = (const bf16x8*)(smem + cur * 16384);
        const bf16x8* Bfp = (const bf16x8*)(smem + cur * 16384 + 8192);
        bf16x8 af[4], bfr[4];
        #pragma unroll
        for (int m = 0; m < 4; ++m) af[m]  = Afp[(wm * 4 + m) * 64 + lane];
        #pragma unroll
        for (int n = 0; n < 4; ++n) bfr[n] = Bfp[(wn * 4 + n) * 64 + lane];
        #pragma unroll
        for (int m = 0; m < 4; ++m)
            #pragma unroll
            for (int n = 0; n < 4; ++n)
                acc[m][n] = __builtin_amdgcn_mfma_f32_16x16x32_bf16(af[m], bfr[n], acc[m][n], 0, 0, 0);
        __builtin_amdgcn_sched_barrier(0);
        __builtin_amdgcn_s_barrier();              // all waves done reading buf cur
        if (kt < 14) STAGE(cur, kt + 2);           // refill it; stays in flight
    }
#undef STAGE

    // epilogue: bias, sum-exp partials (no max), Os staging for coalesced stores
    float pbn[4]; int cvaln[4];
    #pragma unroll
    for (int n = 0; n < 4; ++n) {
        int col = bcol + wn * 64 + n * 16 + lr;
        cvaln[n] = (col < V_);
        pbn[n] = cvaln[n] ? projb[col] : 0.f;
    }
    u16 (*Os)[136] = (u16(*)[136])smem;
    float* ssum = (float*)(smem + 34816);          // [2][128]
    #pragma unroll
    for (int m = 0; m < 4; ++m) {
        #pragma unroll
        for (int i = 0; i < 4; ++i) {
            int row128 = wm * 64 + m * 16 + kq * 4 + i;
            float se = 0.f;
            #pragma unroll
            for (int n = 0; n < 4; ++n) {
                float dv = acc[m][n][i] + pbn[n];
                if (cvaln[n]) se += __expf(dv);
                Os[row128][wn * 64 + n * 16 + lr] = f2bf(dv);
            }
            #pragma unroll
            for (int o = 1; o < 16; o <<= 1) se += __shfl_xor(se, o);
            if (lr == 0) ssum[wn * 128 + row128] = se;
        }
    }
    __syncthreads();
    if (tid < 128) {
        psum[(size_t)(brow + tid) * NT_ + nt] = ssum[tid] + ssum[128 + tid];
    }
    #pragma unroll
    for (int j = 0; j < 8; ++j) {
        int row = j * 16 + (tid >> 4);
        int c8 = (tid & 15) * 8;
        int gcol = bcol + c8;
        if (gcol + 8 <= V_) {                      // V_ % 8 == 0: chunk all-or-nothing
            u16x8 v = *(const u16x8*)&Os[row][c8];
            *(u16x8*)(dec + (size_t)(brow + row) * V_ + gcol) = v;
        }
    }
}

// K4: base[row] = log(sum_i psum_i)
__global__ void k_reduce(const float* __restrict__ psum, float* __restrict__ base) {
    __shared__ float sb[4];
    int row = blockIdx.x;
    int t = threadIdx.x;
    const float* ps = psum + (size_t)row * NT_;
    float s = 0.f;
    for (int j = t; j < NT_; j += 256) s += ps[j];
    s = bsum(s, sb);
    if (t == 0) base[row] = __logf(s);
}

// K5: out = log(p * exp(d - base) + 1e-12), 8 elems/thread
__global__ void k_final(const u16* __restrict__ dec, const float* __restrict__ pgen,
                        const float* __restrict__ base, float* __restrict__ out) {
    int row = blockIdx.y;
    int v0 = (blockIdx.x * 256 + threadIdx.x) * 8;
    if (v0 >= V_) return;
    float p  = pgen[row];
    float bs = base[row];
    u16x8 d = *(const u16x8*)(dec + (size_t)row * V_ + v0);
    float4 o0, o1;
    o0.x = __logf(p * __expf(bf2f(d[0]) - bs) + 1e-12f);
    o0.y = __logf(p * __expf(bf2f(d[1]) - bs) + 1e-12f);
    o0.z = __logf(p * __expf(bf2f(d[2]) - bs) + 1e-12f);
    o0.w = __logf(p * __expf(bf2f(d[3]) - bs) + 1e-12f);
    o1.x = __logf(p * __expf(bf2f(d[4]) - bs) + 1e-12f);
    o1.y = __logf(p * __expf(bf2f(d[5]) - bs) + 1e-12f);
    o1.z = __logf(p * __expf(bf2f(d[6]) - bs) + 1e-12f);
    o1.w = __logf(p * __expf(bf2f(d[7]) - bs) + 1e-12f);
    float* op = out + (size_t)row * V_ + v0;
    *(float4*)op = o0;
    *(float4*)(op + 4) = o1;
}

// K6: overwrite src columns with the pointer-mix term.
// One block per (b,t) row; first-occurrence map + LDS scatter-add of attn row.
__global__ void k_fix(const int* __restrict__ src, const float* __restrict__ attn,
                      const u16* __restrict__ dec, const float* __restrict__ pgen,
                      const float* __restrict__ base, float* __restrict__ out) {
    __shared__ int   sh_sr[S_];
    __shared__ int   sh_fs[S_];
    __shared__ float sh_enc[S_];
    int b = blockIdx.x >> 7;              // grid = B_*T_ = 1024
    int t = blockIdx.x & 127;
    int tid = threadIdx.x;                // 256
    const int* sr = src + b * S_;
    for (int s = tid; s < S_; s += 256) { sh_sr[s] = sr[s]; sh_enc[s] = 0.f; }
    __syncthreads();
    for (int s = tid; s < S_; s += 256) {
        int v = sh_sr[s];
        int f = 0;
        while (sh_sr[f] != v) ++f;        // first occurrence (terminates at s)
        sh_fs[s] = f;
    }
    __syncthreads();
    int row = b * T_ + t;
    const float* ar = attn + (size_t)row * S_;
    for (int s = tid; s < S_; s += 256)
        atomicAdd(&sh_enc[sh_fs[s]], ar[s]);
    __syncthreads();
    float p  = pgen[row];
    float bs = base[row];
    for (int s = tid; s < S_; s += 256) {
        if (sh_fs[s] == s) {
            int v = sh_sr[s];
            float d = bf2f(dec[(size_t)row * V_ + v]);
            out[(size_t)row * V_ + v] =
                __logf(p * __expf(d - bs) + (1.f - p) * sh_enc[s] + 1e-12f);
        }
    }
}

extern "C" void kernel_launch(void* const* d_in, const int* in_sizes, int n_in,
                              void* d_out, int out_size, void* d_ws, size_t ws_size,
                              hipStream_t stream) {
    const float* x    = (const float*)d_in[0];
    const float* xt   = (const float*)d_in[1];
    const float* mem  = (const float*)d_in[2];
    const float* attn = (const float*)d_in[3];
    const int*   src  = (const int*)d_in[4];
    const float* na   = (const float*)d_in[5];
    const float* nb   = (const float*)d_in[6];
    const float* pw   = (const float*)d_in[7];
    const float* pb   = (const float*)d_in[8];
    const float* whw  = (const float*)d_in[9];
    const float* whb  = (const float*)d_in[10];
    const float* wsw  = (const float*)d_in[11];
    const float* wsb  = (const float*)d_in[12];
    const float* wxw  = (const float*)d_in[13];
    const float* wxb  = (const float*)d_in[14];
    const float* bp   = (const float*)d_in[15];

    char* ws = (char*)d_ws;
    u16*   Wb   = (u16*)(ws + 0);                 // 51,200,000 B
    u16*   Ab   = (u16*)(ws + 51200000);          //  1,048,576 B
    u16*   dec  = (u16*)(ws + 52248576);          // 102,400,000 B
    float* psum = (float*)(ws + 154648576);       //  1,601,536 B
    float* mw   = (float*)(ws + 156250112);       //     12,800 B
    float* pgen = (float*)(ws + 156262912);       //      4,096 B
    float* base = (float*)(ws + 156267008);       //      4,096 B
    float* out  = (float*)d_out;
    float* outp = out + (size_t)M_ * V_;          // p_gen section

    k_mw    <<<B_ * S_, 256, 0, stream>>>(mem, whw, mw);
    k_wconv <<<12500, 256, 0, stream>>>(pw, Wb);
    k_rows  <<<M_, 256, 0, stream>>>(x, xt, attn, mw, na, nb, wsw, wxw,
                                     whb, wsb, wxb, bp, Ab, pgen, outp);
    k_gemm  <<<3128, 256, 0, stream>>>(Ab, Wb, pb, dec, psum);
    k_reduce<<<M_, 256, 0, stream>>>(psum, base);
    k_final <<<dim3(25, M_), 256, 0, stream>>>(dec, pgen, base, out);
    k_fix   <<<B_ * T_, 256, 0, stream>>>(src, attn, dec, pgen, base, out);
}